// Round 14
// baseline (229.003 us; speedup 1.0000x reference)
//
#include <hip/hip_runtime.h>
#include <stdint.h>

// ---------- bf16 helpers (storage = unsigned short) ----------
__device__ __forceinline__ float b2f(unsigned short u) {
    union { uint32_t i; float f; } v; v.i = ((uint32_t)u) << 16; return v.f;
}
__device__ __forceinline__ unsigned short f2b(float f) {
    union { float f; uint32_t i; } v; v.f = f;
    uint32_t r = v.i + 0x7fffu + ((v.i >> 16) & 1u);   // RNE
    return (unsigned short)(r >> 16);
}

typedef __bf16 bf16x8 __attribute__((ext_vector_type(8)));
typedef float  f32x16 __attribute__((ext_vector_type(16)));

// ---------------------------------------------------------------------------
// cvt: xb = bf16(x), 8 elems/thread.
// ---------------------------------------------------------------------------
__global__ __launch_bounds__(256)
void cvt_f32_bf16(const float* __restrict__ x, unsigned short* __restrict__ xb) {
    int t = blockIdx.x * 256 + threadIdx.x;
    const float4* p = (const float4*)(x + (size_t)t * 8);
    float4 f0 = p[0], f1 = p[1];
    int4 o;
    o.x = (uint32_t)f2b(f0.x) | ((uint32_t)f2b(f0.y) << 16);
    o.y = (uint32_t)f2b(f0.z) | ((uint32_t)f2b(f0.w) << 16);
    o.z = (uint32_t)f2b(f1.x) | ((uint32_t)f2b(f1.y) << 16);
    o.w = (uint32_t)f2b(f1.z) | ((uint32_t)f2b(f1.w) << 16);
    ((int4*)xb)[t] = o;
}

// ---------------------------------------------------------------------------
// build_T: T[rm=(r1*16+n2)*16+m2][n3][m3] = sum_r2 c1[rm][r2]*c2[(r2*N3+n3)*M3+m3]
// ---------------------------------------------------------------------------
template<int N3, int M3>
__global__ void build_T(const float* __restrict__ c1,
                        const float* __restrict__ c2,
                        float* __restrict__ T) {
    int e = blockIdx.x * 256 + threadIdx.x;
    int m3 = e % M3;
    int t  = e / M3;
    int n3 = t % N3;
    int rm = t / N3;
    float s = 0.f;
#pragma unroll
    for (int r2 = 0; r2 < 16; ++r2)
        s += c1[rm * 16 + r2] * c2[(r2 * N3 + n3) * M3 + m3];
    T[e] = s;
}

// ---------------------------------------------------------------------------
// build_W (coalesced remap): thread t = (((n1*M1+m1)*N2+n2)*M2+m2)*M3+m3.
// ---------------------------------------------------------------------------
template<int N1, int N2, int N3, int M1, int M2, int M3>
__global__ __launch_bounds__(256)
void build_W(const float* __restrict__ c0,
             const float* __restrict__ T,
             unsigned short* __restrict__ W) {
    constexpr int K = N1 * N2 * N3;
    int t  = blockIdx.x * 256 + threadIdx.x;
    int m3 = t % M3;
    int m2 = (t / M3) % M2;
    int n2 = (t / (M3 * M2)) % N2;
    int m1 = (t / (M3 * M2 * N2)) % M1;
    int n1 =  t / (M3 * M2 * N2 * M1);

    float c0r[16];
    const float4* c0p = (const float4*)(c0 + (n1 * M1 + m1) * 16);
#pragma unroll
    for (int i = 0; i < 4; ++i) ((float4*)c0r)[i] = c0p[i];

    float acc[N3] = {};
#pragma unroll
    for (int r1 = 0; r1 < 16; ++r1) {
        const float* Tp = T + (size_t)(((r1 * 16 + n2) * 16 + m2) * N3) * M3 + m3;
#pragma unroll
        for (int n3 = 0; n3 < N3; ++n3)
            acc[n3] += c0r[r1] * Tp[n3 * M3];
    }

    unsigned short ob[N3];
#pragma unroll
    for (int n3 = 0; n3 < N3; ++n3) ob[n3] = f2b(acc[n3]);

    unsigned short* dst = W + (size_t)((m1 * M2 + m2) * M3 + m3) * K
                            + (n1 * N2 + n2) * N3;
#pragma unroll
    for (int c = 0; c < N3 / 8; ++c)
        ((int4*)dst)[c] = ((const int4*)ob)[c];
}

// ---------------------------------------------------------------------------
// GEMM (32x32x16 MFMA, all-waves, tall wave tile): C = A*Bt^T + bias, opt GELU.
// Block BM x BN, 4 waves (2x2), wave tile (BM/2)x(BN/2) = FIxFJ frags of 32x32,
// FI=BM/64, FJ=BN/64. NSUB 64-wide K-subtiles staged per barrier (NSUB=2
// halves the barrier count for deep-K GEMMs).
// LDS swizzle (R13-verified, 0 conflicts): chunk g of row r at slot
//   g ^ (r&7) ^ ((r>>3)&7); store side jj^lr^(c&7); read key
//   (m32&7) ^ ((waveX>>3 + 4*i + (m32>>3)) & 7).
// Register staging only (global_load_lds corrupts at >4 blocks/CU — R7/R8).
// C/D mapping (m74/m101): col=lane&31, row=(reg&3)+8*(reg>>2)+4*(lane>>5).
// Rationale this round: LDS-BW/MAC is the binding resource; FI=4,FJ=2 gives
// 0.047 B/MAC (2x better than FI=FJ=2), balancing LDS (~288cyc) vs MFMA
// (~256cyc) per iter.
// ---------------------------------------------------------------------------
template<int BM, int BN, int NSUB, int KTOT, bool DO_GELU, bool A_F32, bool C_F32>
__global__ __launch_bounds__(256, 2)
void gemm32v2(const void* __restrict__ Av,
              const unsigned short* __restrict__ Bt,
              const float* __restrict__ bias,
              void* __restrict__ Cv,
              int Ncols) {
    constexpr int FI  = BM / 64;
    constexpr int FJ  = BN / 64;
    constexpr int ASZ = BM * 64;
    constexpr int BSZ = BN * 64;
    constexpr int PA  = BM / 32;         // A chunks per wave per subtile
    constexpr int PB  = BN / 32;         // B chunks per wave per subtile
    __shared__ unsigned short As[NSUB * ASZ];
    __shared__ unsigned short Bs[NSUB * BSZ];

    const int tid  = threadIdx.x;
    const int lane = tid & 63;
    const int wave = tid >> 6;
    const int rowBase = blockIdx.y * BM;
    const int colBase = blockIdx.x * BN;

    const int waveM = (wave >> 1) * (BM / 2);
    const int waveN = (wave & 1) * (BN / 2);

    f32x16 acc[FI][FJ] = {};

    const int lr    = lane >> 3;          // local row within 8-row chunk
    const int jj    = lane & 7;           // LDS store slot
    const int m32   = lane & 31;
    const int khalf = lane >> 5;

    for (int k0 = 0; k0 < KTOT; k0 += NSUB * 64) {
        // ---- stage NSUB subtiles
#pragma unroll
        for (int s = 0; s < NSUB; ++s) {
            const int kk = k0 + s * 64;
#pragma unroll
            for (int it = 0; it < PA; ++it) {
                const int c  = wave * PA + it;
                const int jg = jj ^ lr ^ (c & 7);
                const size_t aoff = (size_t)(rowBase + c * 8 + lr) * KTOT + kk + jg * 8;
                int4 v;
                if (A_F32) {
                    const float* ga = (const float*)Av + aoff;
                    float4 f0 = *(const float4*)ga;
                    float4 f1 = *(const float4*)(ga + 4);
                    v.x = (uint32_t)f2b(f0.x) | ((uint32_t)f2b(f0.y) << 16);
                    v.y = (uint32_t)f2b(f0.z) | ((uint32_t)f2b(f0.w) << 16);
                    v.z = (uint32_t)f2b(f1.x) | ((uint32_t)f2b(f1.y) << 16);
                    v.w = (uint32_t)f2b(f1.z) | ((uint32_t)f2b(f1.w) << 16);
                } else {
                    v = *(const int4*)((const unsigned short*)Av + aoff);
                }
                *(int4*)&As[s * ASZ + c * 512 + lane * 8] = v;
            }
#pragma unroll
            for (int it = 0; it < PB; ++it) {
                const int c  = wave * PB + it;
                const int jg = jj ^ lr ^ (c & 7);
                *(int4*)&Bs[s * BSZ + c * 512 + lane * 8] =
                    *(const int4*)(Bt + (size_t)(colBase + c * 8 + lr) * KTOT + kk + jg * 8);
            }
        }
        __syncthreads();

        // ---- compute NSUB subtiles
#pragma unroll
        for (int s = 0; s < NSUB; ++s) {
#pragma unroll
            for (int ks = 0; ks < 4; ++ks) {
                bf16x8 a_f[FI], b_f[FJ];
#pragma unroll
                for (int i = 0; i < FI; ++i) {
                    const int key  = (m32 & 7) ^
                        ((((waveM >> 3) + 4 * i) + (m32 >> 3)) & 7);
                    const int slot = ((ks * 2 + khalf) ^ key) * 8;
                    a_f[i] = *(const bf16x8*)&As[s * ASZ +
                              (waveM + i * 32 + m32) * 64 + slot];
                }
#pragma unroll
                for (int j = 0; j < FJ; ++j) {
                    const int key  = (m32 & 7) ^
                        ((((waveN >> 3) + 4 * j) + (m32 >> 3)) & 7);
                    const int slot = ((ks * 2 + khalf) ^ key) * 8;
                    b_f[j] = *(const bf16x8*)&Bs[s * BSZ +
                              (waveN + j * 32 + m32) * 64 + slot];
                }
#pragma unroll
                for (int i = 0; i < FI; ++i)
#pragma unroll
                    for (int j = 0; j < FJ; ++j)
                        acc[i][j] = __builtin_amdgcn_mfma_f32_32x32x16_bf16(
                            a_f[i], b_f[j], acc[i][j], 0, 0, 0);
            }
        }
        __syncthreads();
    }

    // Epilogue: col=lane&31, row=(reg&3)+8*(reg>>2)+4*khalf
#pragma unroll
    for (int i = 0; i < FI; ++i) {
#pragma unroll
        for (int j = 0; j < FJ; ++j) {
            const int col = colBase + waveN + j * 32 + m32;
            const float bv = bias[col];
#pragma unroll
            for (int reg = 0; reg < 16; ++reg) {
                const int row = rowBase + waveM + i * 32 +
                                (reg & 3) + 8 * (reg >> 2) + 4 * khalf;
                float z = acc[i][j][reg] + bv;
                if (DO_GELU)
                    z = 0.5f * z * (1.f + erff(z * 0.70710678118654752f));
                const size_t off = (size_t)row * Ncols + col;
                if (C_F32) ((float*)Cv)[off] = z;
                else       ((unsigned short*)Cv)[off] = f2b(z);
            }
        }
    }
}

// ---------------------------------------------------------------------------
extern "C" void kernel_launch(void* const* d_in, const int* in_sizes, int n_in,
                              void* d_out, int out_size, void* d_ws, size_t ws_size,
                              hipStream_t stream) {
    const float* x      = (const float*)d_in[0];   // [4096,1024] fp32
    const float* fc1_c0 = (const float*)d_in[1];
    const float* fc1_c1 = (const float*)d_in[2];
    const float* fc1_c2 = (const float*)d_in[3];
    const float* fc1_b  = (const float*)d_in[4];
    const float* fc2_c0 = (const float*)d_in[5];
    const float* fc2_c1 = (const float*)d_in[6];
    const float* fc2_c2 = (const float*)d_in[7];
    const float* fc2_b  = (const float*)d_in[8];

    // Workspace layout (50 MB preferred):
    //   [0,8M)   W    bf16 — W1t [4096][1024], later W2t [1024][4096]
    //   [8,10M)  T    f32 scratch
    //   [10,18M) xb   bf16 copy of x
    //   [18,50M) h    bf16 [4096][4096]
    // Fallback (<50 MB): no xb; GEMM1 repacks fp32 A in-kernel.
    char* ws = (char*)d_ws;
    unsigned short* W  = (unsigned short*)(ws);
    float*          T  = (float*)(ws + (8u << 20));
    const bool big = ws_size >= (50ull << 20);
    unsigned short* xb = (unsigned short*)(ws + (10u << 20));
    unsigned short* h  = (unsigned short*)(ws + (big ? (18u << 20) : (10u << 20)));

    // ---- layer 1: in (8,16,8) -> out (16,16,16)
    build_T<8, 16><<<2048, 256, 0, stream>>>(fc1_c1, fc1_c2, T);
    build_W<8, 16, 8, 16, 16, 16><<<2048, 256, 0, stream>>>(fc1_c0, T, W);
    if (big) {
        cvt_f32_bf16<<<2048, 256, 0, stream>>>(x, xb);
        // GEMM1: 256x128 tile, FI=4/FJ=2, grid 32x16 = 512 blocks (2/CU)
        gemm32v2<256, 128, 1, 1024, true, false, false>
            <<<dim3(32, 16), 256, 0, stream>>>(xb, W, fc1_b, h, 4096);
    } else {
        gemm32v2<256, 128, 1, 1024, true, true, false>
            <<<dim3(32, 16), 256, 0, stream>>>(x, W, fc1_b, h, 4096);
    }

    // ---- layer 2: in (16,16,16) -> out (8,16,8)
    build_T<16, 8><<<2048, 256, 0, stream>>>(fc2_c1, fc2_c2, T);
    build_W<16, 16, 16, 8, 16, 8><<<1024, 256, 0, stream>>>(fc2_c0, T, W);
    // GEMM2: 64x128 tile, FI=1/FJ=2, NSUB=2 (32 barriers), grid 8x64 (2/CU)
    gemm32v2<64, 128, 2, 4096, false, false, true>
        <<<dim3(8, 64), 256, 0, stream>>>(h, W, fc2_b, d_out, 1024);
}